// Round 2
// baseline (829.830 us; speedup 1.0000x reference)
//
#include <hip/hip_runtime.h>

// SJLT projection: out[b, idx[d,j]] += x[b,d] * sign(d,j), * 1/sqrt(4)
// B=64, D=524288, P=8192, C=4.
//
// Strategy: LDS-privatized scatter. Each block owns BT=4 batch rows and a
// 32768-wide D-chunk; accumulates into a 4x8192 fp32 LDS accumulator
// (128 KiB) with ds_add_f32 (plain atomicAdd on direct __shared__ indexing
// -- R1's unsafeAtomicAdd-on-generic-pointer lowered to flat atomics,
// ~200 cyc/instr stall, VALUBusy 1.8%), then flushes *0.5 to global with
// native f32 atomics. Grid = 16 chunks x 16 row-groups = 256 blocks = 1/CU.

constexpr int BATCH  = 64;
constexpr int DIM    = 524288;
constexpr int PROJ   = 8192;

constexpr int BT      = 4;                 // batch rows per block
constexpr int BLOCK   = 1024;              // threads per block (16 waves)
constexpr int DCHUNKS = 16;
constexpr int CHUNK   = DIM / DCHUNKS;     // 32768, divisible by BLOCK
constexpr int ROWG    = BATCH / BT;        // 16

__global__ __launch_bounds__(BLOCK) void sjlt_scatter(
    const float* __restrict__ x,
    const int4*  __restrict__ idx4,   // (DIM) rows of 4 int32 indices
    const int4*  __restrict__ sgn4,   // (DIM) rows of 4 int32 {0,1}
    float*       __restrict__ out)
{
    __shared__ float acc[BT * PROJ];  // 128 KiB

    for (int i = threadIdx.x; i < BT * PROJ; i += BLOCK) acc[i] = 0.0f;
    __syncthreads();

    const int rg   = blockIdx.y;
    const int row0 = rg * BT;
    const int dbeg = blockIdx.x * CHUNK;

    const float* __restrict__ xr0 = x + (size_t)(row0 + 0) * DIM;
    const float* __restrict__ xr1 = x + (size_t)(row0 + 1) * DIM;
    const float* __restrict__ xr2 = x + (size_t)(row0 + 2) * DIM;
    const float* __restrict__ xr3 = x + (size_t)(row0 + 3) * DIM;

    for (int d = dbeg + (int)threadIdx.x; d < dbeg + CHUNK; d += BLOCK) {
        const int4 iv = idx4[d];
        const int4 sv = sgn4[d];
        const float x0 = xr0[d];
        const float x1 = xr1[d];
        const float x2 = xr2[d];
        const float x3 = xr3[d];

        const int p[4] = {iv.x, iv.y, iv.z, iv.w};
        const int s[4] = {sv.x, sv.y, sv.z, sv.w};
#pragma unroll
        for (int j = 0; j < 4; ++j) {
            const float m  = s[j] ? 1.0f : -1.0f;
            const int   pj = p[j];
            // direct __shared__ indexing so infer-address-spaces produces
            // ds_add_f32 (fire-and-forget LDS atomic), NOT flat atomics
            atomicAdd(&acc[pj + 0 * PROJ], m * x0);
            atomicAdd(&acc[pj + 1 * PROJ], m * x1);
            atomicAdd(&acc[pj + 2 * PROJ], m * x2);
            atomicAdd(&acc[pj + 3 * PROJ], m * x3);
        }
    }
    __syncthreads();

    // flush: scale by 1/sqrt(4) = 0.5; 16 chunk-blocks contribute per output.
    // global f32 atomic add is native (fire-and-forget) via unsafeAtomicAdd.
    for (int i = threadIdx.x; i < BT * PROJ; i += BLOCK) {
        const int r  = i >> 13;          // i / PROJ
        const int pp = i & (PROJ - 1);   // i % PROJ
        unsafeAtomicAdd(&out[(size_t)(row0 + r) * PROJ + pp], acc[i] * 0.5f);
    }
}

extern "C" void kernel_launch(void* const* d_in, const int* in_sizes, int n_in,
                              void* d_out, int out_size, void* d_ws, size_t ws_size,
                              hipStream_t stream) {
    const float* x   = (const float*)d_in[0];
    const int4*  idx = (const int4*) d_in[1];
    const int4*  sgn = (const int4*) d_in[2];
    float*       out = (float*)d_out;

    // harness re-poisons d_out to 0xAA before every launch -> zero it
    hipMemsetAsync(d_out, 0, (size_t)out_size * sizeof(float), stream);

    dim3 grid(DCHUNKS, ROWG);
    sjlt_scatter<<<grid, BLOCK, 0, stream>>>(x, idx, sgn, out);
}

// Round 3
// 829.271 us; speedup vs baseline: 1.0007x; 1.0007x over previous
//
#include <hip/hip_runtime.h>

// SJLT projection: out[b, idx[d,j]] += x[b,d] * sign(d,j), * 1/sqrt(4)
// B=64, D=524288, P=8192, C=4.
//
// R1/R2 post-mortem: atomicAdd/unsafeAtomicAdd on LDS f32 both compile to a
// CAS loop (202 cyc/atomic measured; ds_read+ds_cmpst_rtn dependent chain).
// Fix: raw ds_add_f32 via inline asm (no-return, fire-and-forget, 1 DS op).
// LDS address = truncated generic pointer (LLVM flat->local addrspacecast is
// a 32-bit trunc; apertures 4GiB-aligned). Rows 1,3 reached via offset:32768.

constexpr int BATCH  = 64;
constexpr int DIM    = 524288;
constexpr int PROJ   = 8192;

constexpr int BT      = 4;                 // batch rows per block
constexpr int BLOCK   = 1024;              // threads per block (16 waves)
constexpr int DCHUNKS = 16;
constexpr int CHUNK   = DIM / DCHUNKS;     // 32768, divisible by BLOCK
constexpr int ROWG    = BATCH / BT;        // 16

__device__ __forceinline__ void lds_fadd(uint32_t byte_addr, float v) {
    asm volatile("ds_add_f32 %0, %1" :: "v"(byte_addr), "v"(v) : "memory");
}
__device__ __forceinline__ void lds_fadd_off32k(uint32_t byte_addr, float v) {
    asm volatile("ds_add_f32 %0, %1 offset:32768" :: "v"(byte_addr), "v"(v) : "memory");
}

__global__ __launch_bounds__(BLOCK) void sjlt_scatter(
    const float* __restrict__ x,
    const int4*  __restrict__ idx4,   // (DIM) rows of 4 int32 indices
    const int4*  __restrict__ sgn4,   // (DIM) rows of 4 int32 {0,1}
    float*       __restrict__ out)
{
    __shared__ float acc[BT * PROJ];  // 128 KiB

    for (int i = threadIdx.x; i < BT * PROJ; i += BLOCK) acc[i] = 0.0f;
    __syncthreads();

    const int rg   = blockIdx.y;
    const int row0 = rg * BT;
    const int dbeg = blockIdx.x * CHUNK;

    // generic->LDS: 32-bit truncation yields the LDS segment byte offset
    const uint32_t accBase = (uint32_t)(uintptr_t)(&acc[0]);

    const float* __restrict__ xr0 = x + (size_t)(row0 + 0) * DIM;
    const float* __restrict__ xr1 = x + (size_t)(row0 + 1) * DIM;
    const float* __restrict__ xr2 = x + (size_t)(row0 + 2) * DIM;
    const float* __restrict__ xr3 = x + (size_t)(row0 + 3) * DIM;

    for (int d = dbeg + (int)threadIdx.x; d < dbeg + CHUNK; d += BLOCK) {
        const int4 iv = idx4[d];
        const int4 sv = sgn4[d];
        const uint32_t u0 = __float_as_uint(xr0[d]);
        const uint32_t u1 = __float_as_uint(xr1[d]);
        const uint32_t u2 = __float_as_uint(xr2[d]);
        const uint32_t u3 = __float_as_uint(xr3[d]);

        const int p[4] = {iv.x, iv.y, iv.z, iv.w};
        const int s[4] = {sv.x, sv.y, sv.z, sv.w};
#pragma unroll
        for (int j = 0; j < 4; ++j) {
            // s in {0,1}: s==1 -> +x, s==0 -> -x  => xor sign bit with (s^1)<<31
            const uint32_t flip = (uint32_t)(s[j] ^ 1) << 31;
            const uint32_t a01  = accBase + ((uint32_t)p[j] << 2);           // row 0 (row 1 via offset:32768)
            const uint32_t a23  = a01 + 2u * 32768u;                          // row 2 (row 3 via offset:32768)
            lds_fadd        (a01, __uint_as_float(u0 ^ flip));
            lds_fadd_off32k (a01, __uint_as_float(u1 ^ flip));
            lds_fadd        (a23, __uint_as_float(u2 ^ flip));
            lds_fadd_off32k (a23, __uint_as_float(u3 ^ flip));
        }
    }
    __syncthreads();  // lowers to s_waitcnt lgkmcnt(0) + s_barrier -> drains ds_add

    // flush: scale by 1/sqrt(4) = 0.5; 16 chunk-blocks contribute per output.
    for (int i = threadIdx.x; i < BT * PROJ; i += BLOCK) {
        const int r  = i >> 13;          // i / PROJ
        const int pp = i & (PROJ - 1);   // i % PROJ
        unsafeAtomicAdd(&out[(size_t)(row0 + r) * PROJ + pp], acc[i] * 0.5f);
    }
}

extern "C" void kernel_launch(void* const* d_in, const int* in_sizes, int n_in,
                              void* d_out, int out_size, void* d_ws, size_t ws_size,
                              hipStream_t stream) {
    const float* x   = (const float*)d_in[0];
    const int4*  idx = (const int4*) d_in[1];
    const int4*  sgn = (const int4*) d_in[2];
    float*       out = (float*)d_out;

    // harness re-poisons d_out to 0xAA before every launch -> zero it
    hipMemsetAsync(d_out, 0, (size_t)out_size * sizeof(float), stream);

    dim3 grid(DCHUNKS, ROWG);
    sjlt_scatter<<<grid, BLOCK, 0, stream>>>(x, idx, sgn, out);
}

// Round 4
// 432.008 us; speedup vs baseline: 1.9209x; 1.9196x over previous
//
#include <hip/hip_runtime.h>

// SJLT projection: out[b, idx[d,j]] += x[b,d] * sign(d,j), * 1/sqrt(4)
// B=64, D=524288, P=8192, C=4.
//
// R1-R3 post-mortem: LDS fp32 atomics (CAS loop AND raw ds_add_f32) are
// identically capped at ~3.16 cyc/lane-op/CU -> 690 us. The LDS fp-RMW is
// the structural bottleneck. R4 eliminates fp atomics entirely:
//   1. CSR build: histogram -> scan -> scatter entries (int atomics, L2)
//   2. transpose x -> xT[D][64] bf16 (*0.5 folded), coalesced
//   3. gather: wave-per-p, lanes=batch, register accumulation, coalesced
//      256B xT row loads (xT = 64 MiB -> L3-resident on re-reads)
// Fallback to the R3 scatter kernel if ws_size < 72.1 MiB.

constexpr int BATCH = 64;
constexpr int DIM   = 524288;
constexpr int PROJ  = 8192;
constexpr int NENT  = DIM * 4;          // 2,097,152 entries

// ---------------------------------------------------------------- CSR build
__global__ __launch_bounds__(256) void hist_kernel(
    const int4* __restrict__ idx4, uint32_t* __restrict__ cnt)
{
    int d = blockIdx.x * 256 + threadIdx.x;
    int4 iv = idx4[d];
    atomicAdd(&cnt[iv.x], 1u);
    atomicAdd(&cnt[iv.y], 1u);
    atomicAdd(&cnt[iv.z], 1u);
    atomicAdd(&cnt[iv.w], 1u);
}

__global__ __launch_bounds__(1024) void scan_kernel(
    const uint32_t* __restrict__ cnt, uint32_t* __restrict__ cur)
{
    __shared__ uint32_t sums[1024];
    int t = threadIdx.x;
    uint32_t c[8]; uint32_t s = 0;
#pragma unroll
    for (int i = 0; i < 8; ++i) { c[i] = cnt[t * 8 + i]; s += c[i]; }
    sums[t] = s;
    __syncthreads();
    for (int off = 1; off < 1024; off <<= 1) {
        uint32_t v = (t >= off) ? sums[t - off] : 0u;
        __syncthreads();
        sums[t] += v;
        __syncthreads();
    }
    uint32_t base = (t == 0) ? 0u : sums[t - 1];
#pragma unroll
    for (int i = 0; i < 8; ++i) { cur[t * 8 + i] = base; base += c[i]; }
}

__global__ __launch_bounds__(256) void scatter_kernel(
    const int4* __restrict__ idx4, const int4* __restrict__ sgn4,
    uint32_t* __restrict__ cur, uint32_t* __restrict__ entries)
{
    int d = blockIdx.x * 256 + threadIdx.x;
    int4 iv = idx4[d];
    int4 sv = sgn4[d];
    const uint32_t dv = (uint32_t)d << 1;
    uint32_t slot;
    slot = atomicAdd(&cur[iv.x], 1u); entries[slot] = dv | (uint32_t)(sv.x & 1);
    slot = atomicAdd(&cur[iv.y], 1u); entries[slot] = dv | (uint32_t)(sv.y & 1);
    slot = atomicAdd(&cur[iv.z], 1u); entries[slot] = dv | (uint32_t)(sv.z & 1);
    slot = atomicAdd(&cur[iv.w], 1u); entries[slot] = dv | (uint32_t)(sv.w & 1);
}

// ------------------------------------------------------------- transpose
__device__ __forceinline__ uint32_t f2bf(float f) {   // RNE f32 -> bf16 bits
    uint32_t u = __float_as_uint(f);
    return (u + 0x7fffu + ((u >> 16) & 1u)) >> 16;
}

// x (64 x DIM f32) -> xT (DIM x 32 u32), u32 k = bf16(x[2k][d]*.5) | bf16(x[2k+1][d]*.5)<<16
__global__ __launch_bounds__(256) void transpose_kernel(
    const float* __restrict__ x, uint32_t* __restrict__ xT)
{
    __shared__ float tile[64][65];
    const int d0   = blockIdx.x * 64;
    const int lane = threadIdx.x & 63;
    const int q    = threadIdx.x >> 6;      // wave id 0..3
#pragma unroll
    for (int r = 0; r < 16; ++r) {
        int b = r * 4 + q;
        tile[b][lane] = x[(size_t)b * DIM + d0 + lane];
    }
    __syncthreads();
    const int k   = threadIdx.x & 31;       // u32 index in xT row
    const int dl0 = threadIdx.x >> 5;       // 0..7
#pragma unroll
    for (int pass = 0; pass < 8; ++pass) {
        int dl = pass * 8 + dl0;
        uint32_t lo = f2bf(tile[2 * k + 0][dl] * 0.5f);
        uint32_t hi = f2bf(tile[2 * k + 1][dl] * 0.5f);
        xT[(size_t)(d0 + dl) * 32 + k] = lo | (hi << 16);
    }
}

// --------------------------------------------------------------- gather
// wave w handles p: acc over entries [end-cnt, end) of +-xT[d][:]
__global__ __launch_bounds__(256) void gather_kernel(
    const uint32_t* __restrict__ entries, const uint32_t* __restrict__ cnt,
    const uint32_t* __restrict__ endp, const uint32_t* __restrict__ xT,
    float* __restrict__ out)
{
    const int w    = threadIdx.x >> 6;
    const int lane = threadIdx.x & 63;
    const int p    = blockIdx.x * 4 + w;
    const uint32_t n  = cnt[p];
    const uint32_t e0 = endp[p] - n;

    const int half = lane >> 5;     // 0: even entries, 1: odd entries
    const int k    = lane & 31;     // u32 index within xT row (2 batch elems)
    float acc0 = 0.f, acc1 = 0.f;

    for (uint32_t base = 0; base < n; base += 64) {
        uint32_t gi = base + (uint32_t)lane;
        uint32_t ev = (gi < n) ? entries[e0 + gi] : 0u;   // coalesced
        uint32_t m  = n - base; if (m > 64u) m = 64u;
        for (uint32_t t = 0; t < m; t += 2) {
            uint32_t eA = __shfl(ev, (int)t);
            uint32_t eB = __shfl(ev, (int)t + 1);
            uint32_t sel   = half ? eB : eA;
            bool     valid = (base + t + (uint32_t)half) < n;
            sel = valid ? sel : 1u;                 // d=0, s=+ (zeroed below)
            uint32_t d = sel >> 1;
            uint32_t u = xT[(size_t)d * 32 + k];    // 256B/wave, coalesced
            u ^= (sel & 1u) ? 0u : 0x80008000u;     // s=0 -> negate both halves
            u  = valid ? u : 0u;                    // +0.0 pair
            acc0 += __uint_as_float(u << 16);           // b = 2k
            acc1 += __uint_as_float(u & 0xffff0000u);   // b = 2k+1
        }
    }
    acc0 += __shfl_xor(acc0, 32);
    acc1 += __shfl_xor(acc1, 32);
    if (half == 0) {
        out[(size_t)(2 * k + 0) * PROJ + p] = acc0;
        out[(size_t)(2 * k + 1) * PROJ + p] = acc1;
    }
}

// ------------------------------------------------- fallback (R3 scatter)
__device__ __forceinline__ void lds_fadd(uint32_t byte_addr, float v) {
    asm volatile("ds_add_f32 %0, %1" :: "v"(byte_addr), "v"(v) : "memory");
}
__device__ __forceinline__ void lds_fadd_off32k(uint32_t byte_addr, float v) {
    asm volatile("ds_add_f32 %0, %1 offset:32768" :: "v"(byte_addr), "v"(v) : "memory");
}

__global__ __launch_bounds__(1024) void sjlt_scatter(
    const float* __restrict__ x, const int4* __restrict__ idx4,
    const int4* __restrict__ sgn4, float* __restrict__ out)
{
    __shared__ float acc[4 * PROJ];
    for (int i = threadIdx.x; i < 4 * PROJ; i += 1024) acc[i] = 0.0f;
    __syncthreads();
    const int row0 = blockIdx.y * 4;
    const int dbeg = blockIdx.x * (DIM / 16);
    const uint32_t accBase = (uint32_t)(uintptr_t)(&acc[0]);
    const float* xr0 = x + (size_t)(row0 + 0) * DIM;
    const float* xr1 = x + (size_t)(row0 + 1) * DIM;
    const float* xr2 = x + (size_t)(row0 + 2) * DIM;
    const float* xr3 = x + (size_t)(row0 + 3) * DIM;
    for (int d = dbeg + (int)threadIdx.x; d < dbeg + DIM / 16; d += 1024) {
        const int4 iv = idx4[d];
        const int4 sv = sgn4[d];
        const uint32_t u0 = __float_as_uint(xr0[d]);
        const uint32_t u1 = __float_as_uint(xr1[d]);
        const uint32_t u2 = __float_as_uint(xr2[d]);
        const uint32_t u3 = __float_as_uint(xr3[d]);
        const int p[4] = {iv.x, iv.y, iv.z, iv.w};
        const int s[4] = {sv.x, sv.y, sv.z, sv.w};
#pragma unroll
        for (int j = 0; j < 4; ++j) {
            const uint32_t flip = (uint32_t)(s[j] ^ 1) << 31;
            const uint32_t a01  = accBase + ((uint32_t)p[j] << 2);
            const uint32_t a23  = a01 + 2u * 32768u;
            lds_fadd        (a01, __uint_as_float(u0 ^ flip));
            lds_fadd_off32k (a01, __uint_as_float(u1 ^ flip));
            lds_fadd        (a23, __uint_as_float(u2 ^ flip));
            lds_fadd_off32k (a23, __uint_as_float(u3 ^ flip));
        }
    }
    __syncthreads();
    for (int i = threadIdx.x; i < 4 * PROJ; i += 1024) {
        const int r  = i >> 13;
        const int pp = i & (PROJ - 1);
        unsafeAtomicAdd(&out[(size_t)(row0 + r) * PROJ + pp], acc[i] * 0.5f);
    }
}

// --------------------------------------------------------------- launch
extern "C" void kernel_launch(void* const* d_in, const int* in_sizes, int n_in,
                              void* d_out, int out_size, void* d_ws, size_t ws_size,
                              hipStream_t stream) {
    const float* x   = (const float*)d_in[0];
    const int4*  idx = (const int4*) d_in[1];
    const int4*  sgn = (const int4*) d_in[2];
    float*       out = (float*)d_out;

    const size_t need = ((size_t)PROJ + PROJ + NENT + (size_t)DIM * 32) * 4;  // 75,563,008 B
    if (ws_size >= need) {
        uint32_t* cnt     = (uint32_t*)d_ws;
        uint32_t* cur     = cnt + PROJ;
        uint32_t* entries = cur + PROJ;
        uint32_t* xT      = entries + NENT;

        hipMemsetAsync(cnt, 0, PROJ * sizeof(uint32_t), stream);
        hist_kernel     <<<DIM / 256, 256,  0, stream>>>(idx, cnt);
        scan_kernel     <<<1,         1024, 0, stream>>>(cnt, cur);
        scatter_kernel  <<<DIM / 256, 256,  0, stream>>>(idx, sgn, cur, entries);
        transpose_kernel<<<DIM / 64,  256,  0, stream>>>(x, xT);
        gather_kernel   <<<PROJ / 4,  256,  0, stream>>>(entries, cnt, cur, xT, out);
    } else {
        // ws too small: R3 LDS-scatter path (passes at ~830 us)
        hipMemsetAsync(d_out, 0, (size_t)out_size * sizeof(float), stream);
        dim3 grid(16, 16);
        sjlt_scatter<<<grid, 1024, 0, stream>>>(x, idx, sgn, out);
    }
}